// Round 1
// baseline (548.252 us; speedup 1.0000x reference)
//
#include <hip/hip_runtime.h>

// ---------- compile-time Cl(3,0,1) tables ----------
constexpr int pcf(int x){ int c=0; while(x){ c += x&1; x>>=1; } return c; }
constexpr int signexp(int a,int b){ int s=0; a>>=1; while(a){ s += pcf(a&b); a>>=1; } return s&1; }
constexpr float sgnf(int a,int b){ return signexp(a,b) ? -1.0f : 1.0f; }
constexpr float sDf(int a){ return sgnf(a, a^15); }

struct Tbl {
  float gp[16][16];   // sign of g1[a]*g2[b] -> out[a^b], 0 if killed (e0 overlap)
  float jn[16][16];   // sign of j1[a]*j2[b] -> out[a&b], 0 unless a|b==15
};
constexpr Tbl make_tbl(){
  Tbl t{};
  for(int a=0;a<16;a++){
    for(int b=0;b<16;b++){
      t.gp[a][b] = (a & b & 1) ? 0.0f : sgnf(a,b);
      t.jn[a][b] = ((a|b)==15) ? sDf(a)*sDf(b)*sDf(a&b)*sgnf(a^15,b^15) : 0.0f;
    }
  }
  return t;
}
constexpr Tbl TBL = make_tbl();
// grade (popcount) of each blade index
constexpr int PC[16] = {0,1,1,2,1,2,2,3,1,2,2,3,2,3,3,4};

#define P_TILE 8      // positions per block
#define I_CHUNK 4     // input channels staged per LDS chunk

// lds_w layout: [tensor(2)][il(I_CHUNK)][c(64)][b(9)]  -> 2*4*576 floats
// lds_x layout: [p(8)][i(64)*16 + y]                   -> 8*1024 floats

__global__ __launch_bounds__(256) void gbl_fused(
    const float* __restrict__ x, const float* __restrict__ ref,
    const float* __restrict__ wg1, const float* __restrict__ wg2,
    const float* __restrict__ wj1, const float* __restrict__ wj2,
    float* __restrict__ out)
{
  __shared__ float lds_x[P_TILE * 1024];     // 32 KB
  __shared__ float lds_w[2 * I_CHUNK * 576]; // 18 KB

  const int t    = threadIdx.x;
  const int tile = blockIdx.x >> 1;
  const int tau  = blockIdx.x & 1;           // 0: gp pair, 1: jn pair
  const float* __restrict__ w1g = tau ? wj1 : wg1;
  const float* __restrict__ w2g = tau ? wj2 : wg2;

  const int c  = t & 63;   // output channel (lane)
  const int ps = t >> 6;   // wave index 0..3 -> base position slot

  // ---- stage x tile (coalesced float4, LDS layout == global layout) ----
  {
    const float4* __restrict__ gx = (const float4*)(x + (size_t)tile * (P_TILE * 1024));
    float4* lx = (float4*)lds_x;
    #pragma unroll
    for (int k = 0; k < 8; ++k) lx[t + k * 256] = gx[t + k * 256];
  }

  float acc1[2][16], acc2[2][16];
  #pragma unroll
  for (int s = 0; s < 2; ++s) {
    #pragma unroll
    for (int y = 0; y < 16; ++y) { acc1[s][y] = 0.0f; acc2[s][y] = 0.0f; }
  }

  for (int i0 = 0; i0 < 64; i0 += I_CHUNK) {
    __syncthreads();
    // ---- stage weight chunk: w[c][i0..i0+3][0..8] for both tensors ----
    // global per c: 36 consecutive floats starting at c*576 + i0*9
    #pragma unroll
    for (int k = 0; k < 9; ++k) {
      const int e  = t + k * 256;     // 0..2303
      const int cc = e / 36;
      const int r  = e % 36;          // il*9 + b
      const int il = r / 9;
      const int b  = r % 9;
      const float v1 = w1g[cc * 576 + i0 * 9 + r];
      const float v2 = w2g[cc * 576 + i0 * 9 + r];
      lds_w[ il            * 576 + cc * 9 + b] = v1;
      lds_w[(I_CHUNK + il) * 576 + cc * 9 + b] = v2;
    }
    __syncthreads();

    #pragma unroll
    for (int il = 0; il < I_CHUNK; ++il) {
      // per-channel weights (conflict-free: stride 9, gcd(9,32)=1)
      float w1[9], w2[9];
      #pragma unroll
      for (int b = 0; b < 9; ++b) {
        w1[b] = lds_w[ il            * 576 + c * 9 + b];
        w2[b] = lds_w[(I_CHUNK + il) * 576 + c * 9 + b];
      }
      #pragma unroll
      for (int s = 0; s < 2; ++s) {
        const int p = ps + s * 4;
        // wave-uniform address -> pure LDS broadcast reads
        const float4* xr = (const float4*)&lds_x[p * 1024 + (i0 + il) * 16];
        const float4 xa = xr[0], xb = xr[1], xc4 = xr[2], xd = xr[3];
        const float xv[16] = { xa.x, xa.y, xa.z, xa.w,
                               xb.x, xb.y, xb.z, xb.w,
                               xc4.x, xc4.y, xc4.z, xc4.w,
                               xd.x, xd.y, xd.z, xd.w };
        #pragma unroll
        for (int y = 0; y < 16; ++y) {
          acc1[s][y] += w1[PC[y]] * xv[y];
          acc2[s][y] += w2[PC[y]] * xv[y];
        }
        #pragma unroll
        for (int y = 1; y < 16; y += 2) {   // left-e0 maps: x[y^1] -> out[y]
          acc1[s][y] += w1[4 + PC[y]] * xv[y ^ 1];
          acc2[s][y] += w2[4 + PC[y]] * xv[y ^ 1];
        }
      }
    }
  }

  // ---- sparse bilinear (register-resident, fully unrolled) + store ----
  #pragma unroll
  for (int s = 0; s < 2; ++s) {
    const int p = ps + s * 4;
    const size_t pos = (size_t)tile * P_TILE + p;
    float o[16];
    #pragma unroll
    for (int k = 0; k < 16; ++k) o[k] = 0.0f;

    if (tau == 0) {
      #pragma unroll
      for (int a = 0; a < 16; ++a) {
        #pragma unroll
        for (int b = 0; b < 16; ++b) {
          const float sg = TBL.gp[a][b];
          if (sg != 0.0f) o[a ^ b] += sg * acc1[s][a] * acc2[s][b];
        }
      }
      #pragma unroll
      for (int k = 0; k < 16; ++k) o[k] *= 1e-5f;
    } else {
      const float r15 = ref[pos * 16 + 15];
      #pragma unroll
      for (int a = 0; a < 16; ++a) {
        #pragma unroll
        for (int b = 0; b < 16; ++b) {
          const float sg = TBL.jn[a][b];
          if (sg != 0.0f) o[a & b] += sg * acc1[s][a] * acc2[s][b];
        }
      }
      #pragma unroll
      for (int k = 0; k < 16; ++k) o[k] *= r15;
    }

    float4* po = (float4*)(out + (pos * 128 + (size_t)tau * 64 + c) * 16);
    po[0] = make_float4(o[0],  o[1],  o[2],  o[3]);
    po[1] = make_float4(o[4],  o[5],  o[6],  o[7]);
    po[2] = make_float4(o[8],  o[9],  o[10], o[11]);
    po[3] = make_float4(o[12], o[13], o[14], o[15]);
  }
}

extern "C" void kernel_launch(void* const* d_in, const int* in_sizes, int n_in,
                              void* d_out, int out_size, void* d_ws, size_t ws_size,
                              hipStream_t stream) {
  const float* x   = (const float*)d_in[0];
  const float* ref = (const float*)d_in[1];
  const float* wg1 = (const float*)d_in[2];
  const float* wg2 = (const float*)d_in[3];
  const float* wj1 = (const float*)d_in[4];
  const float* wj2 = (const float*)d_in[5];
  float* outp = (float*)d_out;

  const int npos = in_sizes[0] / (64 * 16);        // B*N = 16384
  const int grid = (npos / P_TILE) * 2;            // pos-tiles x {gp, jn}
  gbl_fused<<<grid, 256, 0, stream>>>(x, ref, wg1, wg2, wj1, wj2, outp);
}

// Round 2
// 149.016 us; speedup vs baseline: 3.6792x; 3.6792x over previous
//
#include <hip/hip_runtime.h>

typedef __attribute__((ext_vector_type(4))) float f32x4;
typedef __attribute__((ext_vector_type(8))) short bf16x8;

// ---------- compile-time Cl(3,0,1) tables ----------
constexpr int pcf(int x){ int c=0; while(x){ c += x&1; x>>=1; } return c; }
constexpr int signexp(int a,int b){ int s=0; a>>=1; while(a){ s += pcf(a&b); a>>=1; } return s&1; }
constexpr float sgnf(int a,int b){ return signexp(a,b) ? -1.0f : 1.0f; }
constexpr float sDf(int a){ return sgnf(a, a^15); }

struct Tbl {
  float gp[16][16];   // g1[a]*g2[b] -> out[a^b], 0 if e0 overlap
  float jn[16][16];   // j1[a]*j2[b] -> out[a&b], 0 unless a|b==15
};
constexpr Tbl make_tbl(){
  Tbl t{};
  for(int a=0;a<16;a++){
    for(int b=0;b<16;b++){
      t.gp[a][b] = (a & b & 1) ? 0.0f : sgnf(a,b);
      t.jn[a][b] = ((a|b)==15) ? sDf(a)*sDf(b)*sDf(a&b)*sgnf(a^15,b^15) : 0.0f;
    }
  }
  return t;
}
constexpr Tbl TBL = make_tbl();
constexpr int PC[16] = {0,1,1,2,1,2,2,3,1,2,2,3,2,3,3,4};

__device__ __forceinline__ unsigned short f2bf(float f){
  union { float f; unsigned u; } v; v.f = f;
  unsigned r = v.u + 0x7fffu + ((v.u >> 16) & 1u);   // RNE
  return (unsigned short)(r >> 16);
}

// =====================================================================
// Kernel 1: x[pos][i][y] fp32 -> xt planes, MFMA-A-fragment-linear bf16
// xt elem offset: ((y*np16 + p16)*1024) + kt*512 + lane*8 + j
//   where lane = 16*((i>>3)&3) + pos_local, kt = i>>5, j = i&7
// =====================================================================
__global__ __launch_bounds__(256) void k_xt(const float* __restrict__ x,
                                            unsigned short* __restrict__ xt,
                                            int np16)
{
  const int t = threadIdx.x, w = t >> 6, l = t & 63;
  const int pos = l >> 2, jp = l & 3;
  const int p16 = blockIdx.x;
  const float* src = x + ((size_t)(p16*16 + pos))*1024;

  #pragma unroll
  for (int kt = 0; kt < 2; ++kt) {
    const int i0 = kt*32 + w*8 + jp*2;     // even i; lane covers (i0, i0+1)
    float v[32];
    const float4* s4 = (const float4*)(src + i0*16);
    #pragma unroll
    for (int q = 0; q < 8; ++q) {
      float4 f = s4[q];
      v[q*4+0]=f.x; v[q*4+1]=f.y; v[q*4+2]=f.z; v[q*4+3]=f.w;
    }
    #pragma unroll
    for (int y = 0; y < 16; ++y) {
      unsigned short lo = f2bf(v[y]);       // j = 2*jp   (i0)
      unsigned short hi = f2bf(v[16+y]);    // j = 2*jp+1 (i0+1)
      size_t off = ((size_t)(y*np16 + p16))*1024 + kt*512 + (16*w + pos)*8 + jp*2;
      unsigned int pk = (unsigned)lo | ((unsigned)hi << 16);
      *(unsigned int*)(xt + off) = pk;
    }
  }
}

// =====================================================================
// Kernel 2: weights fp32 -> bf16 B-fragments
// wb offset: ((t*9+b)*8 + nt*2 + kt)*512 + lane*8 + j
//   where nt = c>>4, lane = 16*((i>>3)&3) + (c&15), kt = i>>5, j = i&7
// =====================================================================
__global__ __launch_bounds__(256) void k_wb(const float* __restrict__ wg1,
                                            const float* __restrict__ wg2,
                                            const float* __restrict__ wj1,
                                            const float* __restrict__ wj2,
                                            unsigned short* __restrict__ wb)
{
  const int e = blockIdx.x*256 + threadIdx.x;      // 0 .. 147455
  const int t   = e / 36864;                        // tensor (wave-uniform)
  const int rem = e % 36864;                        // c*576 + i*9 + b
  const int c = rem / 576, r2 = rem % 576, i = r2 / 9, b = r2 % 9;
  const float* wp = (t < 2) ? (t ? wg2 : wg1) : ((t == 2) ? wj1 : wj2);
  const float v = wp[rem];
  const int dst = ((t*9 + b)*8 + (c>>4)*2 + (i>>5))*512
                + (16*((i>>3)&3) + (c&15))*8 + (i&7);
  wb[dst] = f2bf(v);
}

// =====================================================================
// Kernel 3: fused MFMA linears + sparse bilinear + store
// 8 waves: pair = w>>2 (0:gp 1:jn), nt = w&3 (16-channel slice)
// =====================================================================
#define TSEQ 4

__global__ __launch_bounds__(512, 2) void k_main(const unsigned short* __restrict__ xt,
                                                 const unsigned short* __restrict__ wb,
                                                 const float* __restrict__ ref,
                                                 float* __restrict__ out,
                                                 int np16)
{
  __shared__ unsigned short lds[2][16*1024];   // [buf][y*1024 + kt*512 + lane*8 + j]

  const int t = threadIdx.x, w = t >> 6, l = t & 63;
  const int pair = w >> 2, nt = w & 3;
  const int cl = nt*16 + (l & 15);             // channel within 64
  const int t1 = pair*2, t2 = t1 + 1;          // tensor indices
  const int tile0 = blockIdx.x * TSEQ;

  auto stage = [&](int buf, int tile) {
    #pragma unroll
    for (int pl = 0; pl < 2; ++pl) {
      const int y = 2*w + pl;
      #pragma unroll
      for (int ch = 0; ch < 2; ++ch) {
        const unsigned short* g = xt + ((size_t)(y*np16 + tile))*1024 + ch*512 + l*8;
        __builtin_amdgcn_global_load_lds(
            (const __attribute__((address_space(1))) void*)g,
            (__attribute__((address_space(3))) void*)&lds[buf][y*1024 + ch*512],
            16, 0, 0);
      }
    }
  };

  stage(0, tile0);

  for (int s = 0; s < TSEQ; ++s) {
    __syncthreads();                           // publish buf s&1
    if (s + 1 < TSEQ) stage((s + 1) & 1, tile0 + s + 1);
    const int buf = s & 1;

    f32x4 acc1[16], acc2[16];
    #pragma unroll
    for (int y = 0; y < 16; ++y) {
      acc1[y] = (f32x4){0.f,0.f,0.f,0.f};
      acc2[y] = (f32x4){0.f,0.f,0.f,0.f};
    }

    #pragma unroll
    for (int y = 0; y < 16; ++y) {
      #pragma unroll
      for (int kt = 0; kt < 2; ++kt) {
        bf16x8 a  = *(const bf16x8*)&lds[buf][y*1024 + kt*512 + l*8];
        bf16x8 b1 = *(const bf16x8*)(wb + ((size_t)((t1*9 + PC[y])*8 + nt*2 + kt))*512 + l*8);
        bf16x8 b2 = *(const bf16x8*)(wb + ((size_t)((t2*9 + PC[y])*8 + nt*2 + kt))*512 + l*8);
        acc1[y] = __builtin_amdgcn_mfma_f32_16x16x32_bf16(a, b1, acc1[y], 0, 0, 0);
        acc2[y] = __builtin_amdgcn_mfma_f32_16x16x32_bf16(a, b2, acc2[y], 0, 0, 0);
      }
      if (y & 1) {                             // compile-time (y unrolled)
        const int bb = 4 + PC[y];              // left-e0 map, source plane y^1
        #pragma unroll
        for (int kt = 0; kt < 2; ++kt) {
          bf16x8 a  = *(const bf16x8*)&lds[buf][(y^1)*1024 + kt*512 + l*8];
          bf16x8 b1 = *(const bf16x8*)(wb + ((size_t)((t1*9 + bb)*8 + nt*2 + kt))*512 + l*8);
          bf16x8 b2 = *(const bf16x8*)(wb + ((size_t)((t2*9 + bb)*8 + nt*2 + kt))*512 + l*8);
          acc1[y] = __builtin_amdgcn_mfma_f32_16x16x32_bf16(a, b1, acc1[y], 0, 0, 0);
          acc2[y] = __builtin_amdgcn_mfma_f32_16x16x32_bf16(a, b2, acc2[y], 0, 0, 0);
        }
      }
    }

    // ---- lane-local sparse bilinear + store (D: col=lane&15, row=(l>>4)*4+r) ----
    const int tile = tile0 + s;
    #pragma unroll
    for (int r = 0; r < 4; ++r) {
      const int pos = tile*16 + (l >> 4)*4 + r;
      float g1[16], g2[16];
      #pragma unroll
      for (int y = 0; y < 16; ++y) { g1[y] = acc1[y][r]; g2[y] = acc2[y][r]; }
      float o[16];
      #pragma unroll
      for (int k = 0; k < 16; ++k) o[k] = 0.0f;

      if (pair == 0) {
        #pragma unroll
        for (int a = 0; a < 16; ++a)
          #pragma unroll
          for (int b = 0; b < 16; ++b) {
            const float sg = TBL.gp[a][b];
            if (sg != 0.0f) o[a ^ b] += sg * g1[a] * g2[b];
          }
        #pragma unroll
        for (int k = 0; k < 16; ++k) o[k] *= 1e-5f;
      } else {
        const float r15 = ref[(size_t)pos*16 + 15];
        #pragma unroll
        for (int a = 0; a < 16; ++a)
          #pragma unroll
          for (int b = 0; b < 16; ++b) {
            const float sg = TBL.jn[a][b];
            if (sg != 0.0f) o[a & b] += sg * g1[a] * g2[b];
          }
        #pragma unroll
        for (int k = 0; k < 16; ++k) o[k] *= r15;
      }

      float* po = out + ((size_t)pos*128 + pair*64 + cl)*16;
      #pragma unroll
      for (int q = 0; q < 4; ++q)
        *(float4*)(po + q*4) = make_float4(o[q*4], o[q*4+1], o[q*4+2], o[q*4+3]);
    }
  }
}

// =====================================================================
// Fallback: round-0 exact-fp32 scalar kernel (used if ws too small)
// =====================================================================
#define P_TILE 8
#define I_CHUNK 4

__global__ __launch_bounds__(256) void gbl_fused(
    const float* __restrict__ x, const float* __restrict__ ref,
    const float* __restrict__ wg1, const float* __restrict__ wg2,
    const float* __restrict__ wj1, const float* __restrict__ wj2,
    float* __restrict__ out)
{
  __shared__ float lds_x[P_TILE * 1024];
  __shared__ float lds_w[2 * I_CHUNK * 576];

  const int t    = threadIdx.x;
  const int tile = blockIdx.x >> 1;
  const int tau  = blockIdx.x & 1;
  const float* __restrict__ w1g = tau ? wj1 : wg1;
  const float* __restrict__ w2g = tau ? wj2 : wg2;

  const int c  = t & 63;
  const int ps = t >> 6;

  {
    const float4* __restrict__ gx = (const float4*)(x + (size_t)tile * (P_TILE * 1024));
    float4* lx = (float4*)lds_x;
    #pragma unroll
    for (int k = 0; k < 8; ++k) lx[t + k * 256] = gx[t + k * 256];
  }

  float acc1[2][16], acc2[2][16];
  #pragma unroll
  for (int s = 0; s < 2; ++s)
    #pragma unroll
    for (int y = 0; y < 16; ++y) { acc1[s][y] = 0.0f; acc2[s][y] = 0.0f; }

  for (int i0 = 0; i0 < 64; i0 += I_CHUNK) {
    __syncthreads();
    #pragma unroll
    for (int k = 0; k < 9; ++k) {
      const int e  = t + k * 256;
      const int cc = e / 36;
      const int r  = e % 36;
      const int il = r / 9;
      const int b  = r % 9;
      const float v1 = w1g[cc * 576 + i0 * 9 + r];
      const float v2 = w2g[cc * 576 + i0 * 9 + r];
      lds_w[ il            * 576 + cc * 9 + b] = v1;
      lds_w[(I_CHUNK + il) * 576 + cc * 9 + b] = v2;
    }
    __syncthreads();

    #pragma unroll
    for (int il = 0; il < I_CHUNK; ++il) {
      float w1[9], w2[9];
      #pragma unroll
      for (int b = 0; b < 9; ++b) {
        w1[b] = lds_w[ il            * 576 + c * 9 + b];
        w2[b] = lds_w[(I_CHUNK + il) * 576 + c * 9 + b];
      }
      #pragma unroll
      for (int s = 0; s < 2; ++s) {
        const int p = ps + s * 4;
        const float4* xr = (const float4*)&lds_x[p * 1024 + (i0 + il) * 16];
        const float4 xa = xr[0], xb = xr[1], xc4 = xr[2], xd = xr[3];
        const float xv[16] = { xa.x, xa.y, xa.z, xa.w, xb.x, xb.y, xb.z, xb.w,
                               xc4.x, xc4.y, xc4.z, xc4.w, xd.x, xd.y, xd.z, xd.w };
        #pragma unroll
        for (int y = 0; y < 16; ++y) {
          acc1[s][y] += w1[PC[y]] * xv[y];
          acc2[s][y] += w2[PC[y]] * xv[y];
        }
        #pragma unroll
        for (int y = 1; y < 16; y += 2) {
          acc1[s][y] += w1[4 + PC[y]] * xv[y ^ 1];
          acc2[s][y] += w2[4 + PC[y]] * xv[y ^ 1];
        }
      }
    }
  }

  #pragma unroll
  for (int s = 0; s < 2; ++s) {
    const int p = ps + s * 4;
    const size_t pos = (size_t)tile * P_TILE + p;
    float o[16];
    #pragma unroll
    for (int k = 0; k < 16; ++k) o[k] = 0.0f;

    if (tau == 0) {
      #pragma unroll
      for (int a = 0; a < 16; ++a)
        #pragma unroll
        for (int b = 0; b < 16; ++b) {
          const float sg = TBL.gp[a][b];
          if (sg != 0.0f) o[a ^ b] += sg * acc1[s][a] * acc2[s][b];
        }
      #pragma unroll
      for (int k = 0; k < 16; ++k) o[k] *= 1e-5f;
    } else {
      const float r15 = ref[pos * 16 + 15];
      #pragma unroll
      for (int a = 0; a < 16; ++a)
        #pragma unroll
        for (int b = 0; b < 16; ++b) {
          const float sg = TBL.jn[a][b];
          if (sg != 0.0f) o[a & b] += sg * acc1[s][a] * acc2[s][b];
        }
      #pragma unroll
      for (int k = 0; k < 16; ++k) o[k] *= r15;
    }

    float4* po = (float4*)(out + (pos * 128 + (size_t)tau * 64 + c) * 16);
    po[0] = make_float4(o[0],  o[1],  o[2],  o[3]);
    po[1] = make_float4(o[4],  o[5],  o[6],  o[7]);
    po[2] = make_float4(o[8],  o[9],  o[10], o[11]);
    po[3] = make_float4(o[12], o[13], o[14], o[15]);
  }
}

// =====================================================================
extern "C" void kernel_launch(void* const* d_in, const int* in_sizes, int n_in,
                              void* d_out, int out_size, void* d_ws, size_t ws_size,
                              hipStream_t stream) {
  const float* x   = (const float*)d_in[0];
  const float* ref = (const float*)d_in[1];
  const float* wg1 = (const float*)d_in[2];
  const float* wg2 = (const float*)d_in[3];
  const float* wj1 = (const float*)d_in[4];
  const float* wj2 = (const float*)d_in[5];
  float* outp = (float*)d_out;

  const int npos = in_sizes[0] / (64 * 16);     // B*N
  const int np16 = npos / 16;

  const size_t xt_elems = (size_t)npos * 1024;          // 16 planes * npos * 64
  const size_t need = xt_elems * 2 + 294912 * 2;        // xt + wb bytes

  if (ws_size >= need && (npos % (16 * TSEQ)) == 0) {
    unsigned short* xt = (unsigned short*)d_ws;
    unsigned short* wb = xt + xt_elems;
    k_xt  <<<np16, 256, 0, stream>>>(x, xt, np16);
    k_wb  <<<576, 256, 0, stream>>>(wg1, wg2, wj1, wj2, wb);
    k_main<<<np16 / TSEQ, 512, 0, stream>>>(xt, wb, ref, outp, np16);
  } else {
    const int grid = (npos / P_TILE) * 2;
    gbl_fused<<<grid, 256, 0, stream>>>(x, ref, wg1, wg2, wj1, wj2, outp);
  }
}

// Round 3
// 146.301 us; speedup vs baseline: 3.7474x; 1.0186x over previous
//
#include <hip/hip_runtime.h>

typedef unsigned short u16;
typedef unsigned int   u32;
typedef __attribute__((ext_vector_type(4))) float f32x4;
typedef __attribute__((ext_vector_type(8))) short bf16x8;

// ---------- compile-time Cl(3,0,1) tables ----------
constexpr int pcf(int x){ int c=0; while(x){ c += x&1; x>>=1; } return c; }
constexpr int signexp(int a,int b){ int s=0; a>>=1; while(a){ s += pcf(a&b); a>>=1; } return s&1; }
constexpr float sgnf(int a,int b){ return signexp(a,b) ? -1.0f : 1.0f; }
constexpr float sDf(int a){ return sgnf(a, a^15); }

struct Tbl {
  float gp[16][16];   // g1[a]*g2[b] -> out[a^b], 0 if e0 overlap
  float jn[16][16];   // j1[a]*j2[b] -> out[a&b], 0 unless a|b==15
};
constexpr Tbl make_tbl(){
  Tbl t{};
  for(int a=0;a<16;a++){
    for(int b=0;b<16;b++){
      t.gp[a][b] = (a & b & 1) ? 0.0f : sgnf(a,b);
      t.jn[a][b] = ((a|b)==15) ? sDf(a)*sDf(b)*sDf(a&b)*sgnf(a^15,b^15) : 0.0f;
    }
  }
  return t;
}
constexpr Tbl TBL = make_tbl();
constexpr int PC[16] = {0,1,1,2,1,2,2,3,1,2,2,3,2,3,3,4};

__device__ __forceinline__ u16 f2bf(float f){
  union { float f; unsigned u; } v; v.f = f;
  unsigned r = v.u + 0x7fffu + ((v.u >> 16) & 1u);   // RNE
  return (u16)(r >> 16);
}

// =====================================================================
// Kernel: weights fp32 -> bf16 B-fragments
// wb offset: ((t*9+b)*8 + nt*2 + kt)*512 + lane*8 + j
//   nt = c>>4, lane = 16*((i>>3)&3) + (c&15), kt = i>>5, j = i&7
// =====================================================================
__global__ __launch_bounds__(256) void k_wb(const float* __restrict__ wg1,
                                            const float* __restrict__ wg2,
                                            const float* __restrict__ wj1,
                                            const float* __restrict__ wj2,
                                            u16* __restrict__ wb)
{
  const int e = blockIdx.x*256 + threadIdx.x;      // 0 .. 147455
  const int t   = e / 36864;                        // tensor (wave-uniform)
  const int rem = e % 36864;                        // c*576 + i*9 + b
  const int c = rem / 576, r2 = rem % 576, i = r2 / 9, b = r2 % 9;
  const float* wp = (t < 2) ? (t ? wg2 : wg1) : ((t == 2) ? wj1 : wj2);
  const float v = wp[rem];
  const int dst = ((t*9 + b)*8 + (c>>4)*2 + (i>>5))*512
                + (16*((i>>3)&3) + (c&15))*8 + (i&7);
  wb[dst] = f2bf(v);
}

// =====================================================================
// Fused kernel: x transpose (reg->LDS frags) + MFMA linears + bilinear
//               + coalesced epilogue (wave-local LDS transpose)
// 512 thr = 8 waves: pair = w>>2 (0:gp 1:jn), nt = w&3
// Producer role: pp = t&15 (pos), ip = t>>4 (i-pair 0..31)
// =====================================================================
#define TSEQ 2

__global__ __launch_bounds__(512) void k_fused(const float* __restrict__ x,
                                               const u16* __restrict__ wb,
                                               const float* __restrict__ ref,
                                               float* __restrict__ out)
{
  __shared__ __align__(16) u16 lds[2][16384];   // 2 x 32 KB frag buffers

  const int t = threadIdx.x, w = t >> 6, l = t & 63;
  const int pair = w >> 2, nt = w & 3;
  const int t1 = pair*2, t2 = t1 + 1;
  const int tile0 = blockIdx.x * TSEQ;

  // producer mapping (x -> fragment transpose)
  const int pp = t & 15;          // position within 16-pos tile
  const int ip = t >> 4;          // i-pair (i = 2*ip, 2*ip+1)
  // u32 index within a y-plane (512 u32 per plane):
  // kt*256 + (16*((i>>3)&3)+pos)*4 + (ip&3)
  const int d32 = (ip >> 4)*256 + (16*((ip >> 2) & 3) + pp)*4 + (ip & 3);

  float4 X0[8], X1[8];
  {
    const float4* s4 = (const float4*)(x + ((size_t)(tile0*16 + pp))*1024 + ip*32);
    #pragma unroll
    for (int k = 0; k < 8; ++k) X0[k] = s4[k];
  }
  {
    u32* lw = (u32*)&lds[0][0];
    const float* v = (const float*)X0;
    #pragma unroll
    for (int y = 0; y < 16; ++y)
      lw[y*512 + d32] = (u32)f2bf(v[y]) | ((u32)f2bf(v[16 + y]) << 16);
  }
  {
    const float4* s4 = (const float4*)(x + ((size_t)((tile0+1)*16 + pp))*1024 + ip*32);
    #pragma unroll
    for (int k = 0; k < 8; ++k) X1[k] = s4[k];   // in flight across tile-0 MFMA
  }

  for (int s = 0; s < TSEQ; ++s) {
    __syncthreads();                              // frag buf[s&1] published
    const int buf = s & 1;

    f32x4 acc1[16], acc2[16];
    #pragma unroll
    for (int y = 0; y < 16; ++y) {
      acc1[y] = (f32x4){0.f,0.f,0.f,0.f};
      acc2[y] = (f32x4){0.f,0.f,0.f,0.f};
    }

    #pragma unroll
    for (int y = 0; y < 16; ++y) {
      #pragma unroll
      for (int kt = 0; kt < 2; ++kt) {
        bf16x8 a  = *(const bf16x8*)&lds[buf][y*1024 + kt*512 + l*8];
        bf16x8 b1 = *(const bf16x8*)(wb + ((size_t)((t1*9 + PC[y])*8 + nt*2 + kt))*512 + l*8);
        bf16x8 b2 = *(const bf16x8*)(wb + ((size_t)((t2*9 + PC[y])*8 + nt*2 + kt))*512 + l*8);
        acc1[y] = __builtin_amdgcn_mfma_f32_16x16x32_bf16(a, b1, acc1[y], 0, 0, 0);
        acc2[y] = __builtin_amdgcn_mfma_f32_16x16x32_bf16(a, b2, acc2[y], 0, 0, 0);
      }
      if (y & 1) {                                // left-e0 map, source plane y^1
        const int bb = 4 + PC[y];
        #pragma unroll
        for (int kt = 0; kt < 2; ++kt) {
          bf16x8 a  = *(const bf16x8*)&lds[buf][(y^1)*1024 + kt*512 + l*8];
          bf16x8 b1 = *(const bf16x8*)(wb + ((size_t)((t1*9 + bb)*8 + nt*2 + kt))*512 + l*8);
          bf16x8 b2 = *(const bf16x8*)(wb + ((size_t)((t2*9 + bb)*8 + nt*2 + kt))*512 + l*8);
          acc1[y] = __builtin_amdgcn_mfma_f32_16x16x32_bf16(a, b1, acc1[y], 0, 0, 0);
          acc2[y] = __builtin_amdgcn_mfma_f32_16x16x32_bf16(a, b2, acc2[y], 0, 0, 0);
        }
      }
    }

    __syncthreads();   // all MFMA reads of buf done -> reusable as scratch

    if (s == 0) {      // stage tile 1 fragments into buf 1 (other buffer)
      u32* lw = (u32*)&lds[1][0];
      const float* v = (const float*)X1;
      #pragma unroll
      for (int y = 0; y < 16; ++y)
        lw[y*512 + d32] = (u32)f2bf(v[y]) | ((u32)f2bf(v[16 + y]) << 16);
    }

    // ---- epilogue: bilinear + wave-local LDS transpose + coalesced store
    const int tile = tile0 + s;
    f32x4* scr = (f32x4*)&lds[buf][0];            // 8 waves x 256 f32x4 (4 KB each)
    const int pg = l >> 4, c16 = l & 15;

    #pragma unroll
    for (int r = 0; r < 4; ++r) {
      float g1[16], g2[16];
      #pragma unroll
      for (int y = 0; y < 16; ++y) { g1[y] = acc1[y][r]; g2[y] = acc2[y][r]; }
      float o[16];
      #pragma unroll
      for (int k = 0; k < 16; ++k) o[k] = 0.0f;

      if (pair == 0) {
        #pragma unroll
        for (int a = 0; a < 16; ++a)
          #pragma unroll
          for (int b = 0; b < 16; ++b) {
            const float sg = TBL.gp[a][b];
            if (sg != 0.0f) o[a ^ b] += sg * g1[a] * g2[b];
          }
        #pragma unroll
        for (int k = 0; k < 16; ++k) o[k] *= 1e-5f;
      } else {
        const float r15 = ref[(size_t)(tile*16 + pg*4 + r)*16 + 15];
        #pragma unroll
        for (int a = 0; a < 16; ++a)
          #pragma unroll
          for (int b = 0; b < 16; ++b) {
            const float sg = TBL.jn[a][b];
            if (sg != 0.0f) o[a & b] += sg * g1[a] * g2[b];
          }
        #pragma unroll
        for (int k = 0; k < 16; ++k) o[k] *= r15;
      }

      // write 4 f32x4 into wave-private swizzled scratch
      #pragma unroll
      for (int j = 0; j < 4; ++j) {
        const int loc = pg*64 + c16*4 + j;
        const int f4s = loc ^ ((loc >> 3) & 7);
        scr[w*256 + f4s] = (f32x4){o[j*4], o[j*4+1], o[j*4+2], o[j*4+3]};
      }
      asm volatile("s_waitcnt lgkmcnt(0)" ::: "memory");
      __builtin_amdgcn_sched_barrier(0);

      // read back linear (swizzled) and store coalesced: 1 KB / wave-instruction
      #pragma unroll
      for (int q = 0; q < 4; ++q) {
        const int loc = q*64 + l;
        const int f4s = loc ^ ((loc >> 3) & 7);
        const f32x4 v = scr[w*256 + f4s];
        float4* dst = (float4*)(out + ((size_t)(tile*16 + q*4 + r)*128 + pair*64 + nt*16)*16) + l;
        *dst = make_float4(v[0], v[1], v[2], v[3]);
      }
      asm volatile("s_waitcnt lgkmcnt(0)" ::: "memory");
      __builtin_amdgcn_sched_barrier(0);
    }
  }
}

// =====================================================================
// Fallback: exact-fp32 scalar kernel (used if ws too small / odd shape)
// =====================================================================
#define P_TILE 8
#define I_CHUNK 4

__global__ __launch_bounds__(256) void gbl_fused(
    const float* __restrict__ x, const float* __restrict__ ref,
    const float* __restrict__ wg1, const float* __restrict__ wg2,
    const float* __restrict__ wj1, const float* __restrict__ wj2,
    float* __restrict__ out)
{
  __shared__ float lds_x[P_TILE * 1024];
  __shared__ float lds_w[2 * I_CHUNK * 576];

  const int t    = threadIdx.x;
  const int tile = blockIdx.x >> 1;
  const int tau  = blockIdx.x & 1;
  const float* __restrict__ w1g = tau ? wj1 : wg1;
  const float* __restrict__ w2g = tau ? wj2 : wg2;

  const int c  = t & 63;
  const int ps = t >> 6;

  {
    const float4* __restrict__ gx = (const float4*)(x + (size_t)tile * (P_TILE * 1024));
    float4* lx = (float4*)lds_x;
    #pragma unroll
    for (int k = 0; k < 8; ++k) lx[t + k * 256] = gx[t + k * 256];
  }

  float acc1[2][16], acc2[2][16];
  #pragma unroll
  for (int s = 0; s < 2; ++s)
    #pragma unroll
    for (int y = 0; y < 16; ++y) { acc1[s][y] = 0.0f; acc2[s][y] = 0.0f; }

  for (int i0 = 0; i0 < 64; i0 += I_CHUNK) {
    __syncthreads();
    #pragma unroll
    for (int k = 0; k < 9; ++k) {
      const int e  = t + k * 256;
      const int cc = e / 36;
      const int r  = e % 36;
      const int il = r / 9;
      const int b  = r % 9;
      lds_w[ il            * 576 + cc * 9 + b] = w1g[cc * 576 + i0 * 9 + r];
      lds_w[(I_CHUNK + il) * 576 + cc * 9 + b] = w2g[cc * 576 + i0 * 9 + r];
    }
    __syncthreads();

    #pragma unroll
    for (int il = 0; il < I_CHUNK; ++il) {
      float w1[9], w2[9];
      #pragma unroll
      for (int b = 0; b < 9; ++b) {
        w1[b] = lds_w[ il            * 576 + c * 9 + b];
        w2[b] = lds_w[(I_CHUNK + il) * 576 + c * 9 + b];
      }
      #pragma unroll
      for (int s = 0; s < 2; ++s) {
        const int p = ps + s * 4;
        const float4* xr = (const float4*)&lds_x[p * 1024 + (i0 + il) * 16];
        const float4 xa = xr[0], xb = xr[1], xc4 = xr[2], xd = xr[3];
        const float xv[16] = { xa.x, xa.y, xa.z, xa.w, xb.x, xb.y, xb.z, xb.w,
                               xc4.x, xc4.y, xc4.z, xc4.w, xd.x, xd.y, xd.z, xd.w };
        #pragma unroll
        for (int y = 0; y < 16; ++y) {
          acc1[s][y] += w1[PC[y]] * xv[y];
          acc2[s][y] += w2[PC[y]] * xv[y];
        }
        #pragma unroll
        for (int y = 1; y < 16; y += 2) {
          acc1[s][y] += w1[4 + PC[y]] * xv[y ^ 1];
          acc2[s][y] += w2[4 + PC[y]] * xv[y ^ 1];
        }
      }
    }
  }

  #pragma unroll
  for (int s = 0; s < 2; ++s) {
    const int p = ps + s * 4;
    const size_t pos = (size_t)tile * P_TILE + p;
    float o[16];
    #pragma unroll
    for (int k = 0; k < 16; ++k) o[k] = 0.0f;

    if (tau == 0) {
      #pragma unroll
      for (int a = 0; a < 16; ++a)
        #pragma unroll
        for (int b = 0; b < 16; ++b) {
          const float sg = TBL.gp[a][b];
          if (sg != 0.0f) o[a ^ b] += sg * acc1[s][a] * acc2[s][b];
        }
      #pragma unroll
      for (int k = 0; k < 16; ++k) o[k] *= 1e-5f;
    } else {
      const float r15 = ref[pos * 16 + 15];
      #pragma unroll
      for (int a = 0; a < 16; ++a)
        #pragma unroll
        for (int b = 0; b < 16; ++b) {
          const float sg = TBL.jn[a][b];
          if (sg != 0.0f) o[a & b] += sg * acc1[s][a] * acc2[s][b];
        }
      #pragma unroll
      for (int k = 0; k < 16; ++k) o[k] *= r15;
    }

    float4* po = (float4*)(out + (pos * 128 + (size_t)tau * 64 + c) * 16);
    po[0] = make_float4(o[0],  o[1],  o[2],  o[3]);
    po[1] = make_float4(o[4],  o[5],  o[6],  o[7]);
    po[2] = make_float4(o[8],  o[9],  o[10], o[11]);
    po[3] = make_float4(o[12], o[13], o[14], o[15]);
  }
}

// =====================================================================
extern "C" void kernel_launch(void* const* d_in, const int* in_sizes, int n_in,
                              void* d_out, int out_size, void* d_ws, size_t ws_size,
                              hipStream_t stream) {
  const float* x   = (const float*)d_in[0];
  const float* ref = (const float*)d_in[1];
  const float* wg1 = (const float*)d_in[2];
  const float* wg2 = (const float*)d_in[3];
  const float* wj1 = (const float*)d_in[4];
  const float* wj2 = (const float*)d_in[5];
  float* outp = (float*)d_out;

  const int npos = in_sizes[0] / (64 * 16);     // B*N

  if (ws_size >= 294912 && (npos % (16 * TSEQ)) == 0) {
    u16* wb = (u16*)d_ws;
    k_wb   <<<576, 256, 0, stream>>>(wg1, wg2, wj1, wj2, wb);
    k_fused<<<npos / (16 * TSEQ), 512, 0, stream>>>(x, wb, ref, outp);
  } else {
    const int grid = (npos / P_TILE) * 2;
    gbl_fused<<<grid, 256, 0, stream>>>(x, ref, wg1, wg2, wj1, wj2, outp);
  }
}

// Round 4
// 68.799 us; speedup vs baseline: 7.9689x; 2.1265x over previous
//
#include <hip/hip_runtime.h>

typedef unsigned short u16;
typedef unsigned int   u32;
typedef __attribute__((ext_vector_type(4))) float f32x4;
typedef __attribute__((ext_vector_type(8))) short bf16x8;

// ---------- compile-time Cl(3,0,1) tables ----------
constexpr int pcf(int x){ int c=0; while(x){ c += x&1; x>>=1; } return c; }
constexpr int signexp(int a,int b){ int s=0; a>>=1; while(a){ s += pcf(a&b); a>>=1; } return s&1; }
constexpr float sgnf(int a,int b){ return signexp(a,b) ? -1.0f : 1.0f; }
constexpr float sDf(int a){ return sgnf(a, a^15); }

struct Tbl {
  float gp[16][16];   // g1[a]*g2[b] -> out[a^b], 0 if e0 overlap
  float jn[16][16];   // j1[a]*j2[b] -> out[a&b], 0 unless a|b==15
};
constexpr Tbl make_tbl(){
  Tbl t{};
  for(int a=0;a<16;a++){
    for(int b=0;b<16;b++){
      t.gp[a][b] = (a & b & 1) ? 0.0f : sgnf(a,b);
      t.jn[a][b] = ((a|b)==15) ? sDf(a)*sDf(b)*sDf(a&b)*sgnf(a^15,b^15) : 0.0f;
    }
  }
  return t;
}
constexpr Tbl TBL = make_tbl();
constexpr int PC[16] = {0,1,1,2,1,2,2,3,1,2,2,3,2,3,3,4};

__device__ __forceinline__ u16 f2bf(float f){
  union { float f; unsigned u; } v; v.f = f;
  unsigned r = v.u + 0x7fffu + ((v.u >> 16) & 1u);   // RNE
  return (u16)(r >> 16);
}

// =====================================================================
// Kernel: weights fp32 -> bf16 B-fragments
// wb offset: ((t*9+b)*8 + nt*2 + kt)*512 + lane*8 + j
//   nt = c>>4, lane = 16*((i>>3)&3) + (c&15), kt = i>>5, j = i&7
// =====================================================================
__global__ __launch_bounds__(256) void k_wb(const float* __restrict__ wg1,
                                            const float* __restrict__ wg2,
                                            const float* __restrict__ wj1,
                                            const float* __restrict__ wj2,
                                            u16* __restrict__ wb)
{
  const int e = blockIdx.x*256 + threadIdx.x;      // 0 .. 147455
  const int t   = e / 36864;                        // tensor (wave-uniform)
  const int rem = e % 36864;                        // c*576 + i*9 + b
  const int c = rem / 576, r2 = rem % 576, i = r2 / 9, b = r2 % 9;
  const float* wp = (t < 2) ? (t ? wg2 : wg1) : ((t == 2) ? wj1 : wj2);
  const float v = wp[rem];
  const int dst = ((t*9 + b)*8 + (c>>4)*2 + (i>>5))*512
                + (16*((i>>3)&3) + (c&15))*8 + (i&7);
  wb[dst] = f2bf(v);
}

// =====================================================================
// Fused kernel, one 16-pos tile per block (no cross-tile register state
// -> no spill). 512 thr = 8 waves: pair = w>>2 (0:gp 1:jn), nt = w&3.
// Phase 1: x -> bf16 fragment transpose via registers -> LDS
// Phase 2: 96 MFMA/wave (A from LDS, B fragments from L2-resident wb)
// Phase 3: bilinear (lane-local) + wave-local LDS transpose + 1KB stores
// =====================================================================
__global__ __launch_bounds__(512) void k_fused(const float* __restrict__ x,
                                               const u16* __restrict__ wb,
                                               const float* __restrict__ ref,
                                               float* __restrict__ out)
{
  __shared__ __align__(16) u16 lds[16384];   // 32 KB: frag buffer, then scratch

  const int t = threadIdx.x, w = t >> 6, l = t & 63;
  const int pair = w >> 2, nt = w & 3;
  const int t1 = pair*2, t2 = t1 + 1;
  const int tile = blockIdx.x;

  // ---- phase 1: producer transpose. thread: pp = t&15 (pos), ip = t>>4
  {
    const int pp = t & 15;
    const int ip = t >> 4;                   // i-pair (i = 2*ip, 2*ip+1)
    // u32 slot within a y-plane (512 u32/plane):
    // kt*256 + (16*((i>>3)&3)+pos)*4 + (ip&3)
    const int d32 = (ip >> 4)*256 + (16*((ip >> 2) & 3) + pp)*4 + (ip & 3);

    float4 X0[8];
    const float4* s4 = (const float4*)(x + ((size_t)(tile*16 + pp))*1024 + ip*32);
    #pragma unroll
    for (int k = 0; k < 8; ++k) X0[k] = s4[k];

    u32* lw = (u32*)lds;
    const float* v = (const float*)X0;
    #pragma unroll
    for (int y = 0; y < 16; ++y)
      lw[y*512 + d32] = (u32)f2bf(v[y]) | ((u32)f2bf(v[16 + y]) << 16);
  }

  __syncthreads();                           // fragments published

  // ---- phase 2: MFMA linears ----
  f32x4 acc1[16], acc2[16];
  #pragma unroll
  for (int y = 0; y < 16; ++y) {
    acc1[y] = (f32x4){0.f,0.f,0.f,0.f};
    acc2[y] = (f32x4){0.f,0.f,0.f,0.f};
  }

  #pragma unroll
  for (int y = 0; y < 16; ++y) {
    #pragma unroll
    for (int kt = 0; kt < 2; ++kt) {
      bf16x8 a  = *(const bf16x8*)&lds[y*1024 + kt*512 + l*8];
      bf16x8 b1 = *(const bf16x8*)(wb + ((size_t)((t1*9 + PC[y])*8 + nt*2 + kt))*512 + l*8);
      bf16x8 b2 = *(const bf16x8*)(wb + ((size_t)((t2*9 + PC[y])*8 + nt*2 + kt))*512 + l*8);
      acc1[y] = __builtin_amdgcn_mfma_f32_16x16x32_bf16(a, b1, acc1[y], 0, 0, 0);
      acc2[y] = __builtin_amdgcn_mfma_f32_16x16x32_bf16(a, b2, acc2[y], 0, 0, 0);
    }
    if (y & 1) {                             // left-e0 map, source plane y^1
      const int bb = 4 + PC[y];
      #pragma unroll
      for (int kt = 0; kt < 2; ++kt) {
        bf16x8 a  = *(const bf16x8*)&lds[(y^1)*1024 + kt*512 + l*8];
        bf16x8 b1 = *(const bf16x8*)(wb + ((size_t)((t1*9 + bb)*8 + nt*2 + kt))*512 + l*8);
        bf16x8 b2 = *(const bf16x8*)(wb + ((size_t)((t2*9 + bb)*8 + nt*2 + kt))*512 + l*8);
        acc1[y] = __builtin_amdgcn_mfma_f32_16x16x32_bf16(a, b1, acc1[y], 0, 0, 0);
        acc2[y] = __builtin_amdgcn_mfma_f32_16x16x32_bf16(a, b2, acc2[y], 0, 0, 0);
      }
    }
  }

  __syncthreads();   // all MFMA reads done -> LDS reusable as scratch

  // ---- phase 3: bilinear + wave-local LDS transpose + coalesced store
  f32x4* scr = (f32x4*)lds;                  // 8 waves x 256 f32x4 (4 KB each)
  const int pg = l >> 4, c16 = l & 15;

  #pragma unroll
  for (int r = 0; r < 4; ++r) {
    float g1[16], g2[16];
    #pragma unroll
    for (int y = 0; y < 16; ++y) { g1[y] = acc1[y][r]; g2[y] = acc2[y][r]; }
    float o[16];
    #pragma unroll
    for (int k = 0; k < 16; ++k) o[k] = 0.0f;

    if (pair == 0) {
      #pragma unroll
      for (int a = 0; a < 16; ++a)
        #pragma unroll
        for (int b = 0; b < 16; ++b) {
          const float sg = TBL.gp[a][b];
          if (sg != 0.0f) o[a ^ b] += sg * g1[a] * g2[b];
        }
      #pragma unroll
      for (int k = 0; k < 16; ++k) o[k] *= 1e-5f;
    } else {
      const float r15 = ref[(size_t)(tile*16 + pg*4 + r)*16 + 15];
      #pragma unroll
      for (int a = 0; a < 16; ++a)
        #pragma unroll
        for (int b = 0; b < 16; ++b) {
          const float sg = TBL.jn[a][b];
          if (sg != 0.0f) o[a & b] += sg * g1[a] * g2[b];
        }
      #pragma unroll
      for (int k = 0; k < 16; ++k) o[k] *= r15;
    }

    // write 4 f32x4 into wave-private swizzled scratch
    #pragma unroll
    for (int j = 0; j < 4; ++j) {
      const int loc = pg*64 + c16*4 + j;
      const int f4s = loc ^ ((loc >> 3) & 7);
      scr[w*256 + f4s] = (f32x4){o[j*4], o[j*4+1], o[j*4+2], o[j*4+3]};
    }

    // read back (same swizzle) and store coalesced: 1 KB / wave-instruction
    #pragma unroll
    for (int q = 0; q < 4; ++q) {
      const int loc = q*64 + l;
      const int f4s = loc ^ ((loc >> 3) & 7);
      const f32x4 v = scr[w*256 + f4s];
      float4* dst = (float4*)(out + ((size_t)(tile*16 + q*4 + r)*128 + pair*64 + nt*16)*16) + l;
      *dst = make_float4(v[0], v[1], v[2], v[3]);
    }
  }
}

// =====================================================================
// Fallback: exact-fp32 scalar kernel (used if ws too small / odd shape)
// =====================================================================
#define P_TILE 8
#define I_CHUNK 4

__global__ __launch_bounds__(256) void gbl_fused(
    const float* __restrict__ x, const float* __restrict__ ref,
    const float* __restrict__ wg1, const float* __restrict__ wg2,
    const float* __restrict__ wj1, const float* __restrict__ wj2,
    float* __restrict__ out)
{
  __shared__ float lds_x[P_TILE * 1024];
  __shared__ float lds_w[2 * I_CHUNK * 576];

  const int t    = threadIdx.x;
  const int tile = blockIdx.x >> 1;
  const int tau  = blockIdx.x & 1;
  const float* __restrict__ w1g = tau ? wj1 : wg1;
  const float* __restrict__ w2g = tau ? wj2 : wg2;

  const int c  = t & 63;
  const int ps = t >> 6;

  {
    const float4* __restrict__ gx = (const float4*)(x + (size_t)tile * (P_TILE * 1024));
    float4* lx = (float4*)lds_x;
    #pragma unroll
    for (int k = 0; k < 8; ++k) lx[t + k * 256] = gx[t + k * 256];
  }

  float acc1[2][16], acc2[2][16];
  #pragma unroll
  for (int s = 0; s < 2; ++s)
    #pragma unroll
    for (int y = 0; y < 16; ++y) { acc1[s][y] = 0.0f; acc2[s][y] = 0.0f; }

  for (int i0 = 0; i0 < 64; i0 += I_CHUNK) {
    __syncthreads();
    #pragma unroll
    for (int k = 0; k < 9; ++k) {
      const int e  = t + k * 256;
      const int cc = e / 36;
      const int r  = e % 36;
      const int il = r / 9;
      const int b  = r % 9;
      lds_w[ il            * 576 + cc * 9 + b] = w1g[cc * 576 + i0 * 9 + r];
      lds_w[(I_CHUNK + il) * 576 + cc * 9 + b] = w2g[cc * 576 + i0 * 9 + r];
    }
    __syncthreads();

    #pragma unroll
    for (int il = 0; il < I_CHUNK; ++il) {
      float w1[9], w2[9];
      #pragma unroll
      for (int b = 0; b < 9; ++b) {
        w1[b] = lds_w[ il            * 576 + c * 9 + b];
        w2[b] = lds_w[(I_CHUNK + il) * 576 + c * 9 + b];
      }
      #pragma unroll
      for (int s = 0; s < 2; ++s) {
        const int p = ps + s * 4;
        const float4* xr = (const float4*)&lds_x[p * 1024 + (i0 + il) * 16];
        const float4 xa = xr[0], xb = xr[1], xc4 = xr[2], xd = xr[3];
        const float xv[16] = { xa.x, xa.y, xa.z, xa.w, xb.x, xb.y, xb.z, xb.w,
                               xc4.x, xc4.y, xc4.z, xc4.w, xd.x, xd.y, xd.z, xd.w };
        #pragma unroll
        for (int y = 0; y < 16; ++y) {
          acc1[s][y] += w1[PC[y]] * xv[y];
          acc2[s][y] += w2[PC[y]] * xv[y];
        }
        #pragma unroll
        for (int y = 1; y < 16; y += 2) {
          acc1[s][y] += w1[4 + PC[y]] * xv[y ^ 1];
          acc2[s][y] += w2[4 + PC[y]] * xv[y ^ 1];
        }
      }
    }
  }

  #pragma unroll
  for (int s = 0; s < 2; ++s) {
    const int p = ps + s * 4;
    const size_t pos = (size_t)tile * P_TILE + p;
    float o[16];
    #pragma unroll
    for (int k = 0; k < 16; ++k) o[k] = 0.0f;

    if (tau == 0) {
      #pragma unroll
      for (int a = 0; a < 16; ++a)
        #pragma unroll
        for (int b = 0; b < 16; ++b) {
          const float sg = TBL.gp[a][b];
          if (sg != 0.0f) o[a ^ b] += sg * acc1[s][a] * acc2[s][b];
        }
      #pragma unroll
      for (int k = 0; k < 16; ++k) o[k] *= 1e-5f;
    } else {
      const float r15 = ref[pos * 16 + 15];
      #pragma unroll
      for (int a = 0; a < 16; ++a)
        #pragma unroll
        for (int b = 0; b < 16; ++b) {
          const float sg = TBL.jn[a][b];
          if (sg != 0.0f) o[a & b] += sg * acc1[s][a] * acc2[s][b];
        }
      #pragma unroll
      for (int k = 0; k < 16; ++k) o[k] *= r15;
    }

    float4* po = (float4*)(out + (pos * 128 + (size_t)tau * 64 + c) * 16);
    po[0] = make_float4(o[0],  o[1],  o[2],  o[3]);
    po[1] = make_float4(o[4],  o[5],  o[6],  o[7]);
    po[2] = make_float4(o[8],  o[9],  o[10], o[11]);
    po[3] = make_float4(o[12], o[13], o[14], o[15]);
  }
}

// =====================================================================
extern "C" void kernel_launch(void* const* d_in, const int* in_sizes, int n_in,
                              void* d_out, int out_size, void* d_ws, size_t ws_size,
                              hipStream_t stream) {
  const float* x   = (const float*)d_in[0];
  const float* ref = (const float*)d_in[1];
  const float* wg1 = (const float*)d_in[2];
  const float* wg2 = (const float*)d_in[3];
  const float* wj1 = (const float*)d_in[4];
  const float* wj2 = (const float*)d_in[5];
  float* outp = (float*)d_out;

  const int npos = in_sizes[0] / (64 * 16);     // B*N

  if (ws_size >= 294912 && (npos % 16) == 0) {
    u16* wb = (u16*)d_ws;
    k_wb   <<<576, 256, 0, stream>>>(wg1, wg2, wj1, wj2, wb);
    k_fused<<<npos / 16, 512, 0, stream>>>(x, wb, ref, outp);
  } else {
    const int grid = (npos / P_TILE) * 2;
    gbl_fused<<<grid, 256, 0, stream>>>(x, ref, wg1, wg2, wj1, wj2, outp);
  }
}